// Round 7
// baseline (217.420 us; speedup 1.0000x reference)
//
#include <hip/hip_runtime.h>
#include <hip/hip_bf16.h>

#define M_SAMP 4096
#define D_IN   100
#define HID    256
#define IN_DIM 101
#define NSQ    10000   // 100*100
#define NPAD   10112   // 79*128, padded rows of P
#define SMF    4       // samples per fwd block
#define NFWD   (M_SAMP / SMF)   // 1024 fwd blocks

typedef __attribute__((ext_vector_type(8))) short short8;
typedef __attribute__((ext_vector_type(4))) float f32x4;

// async global->LDS, 16B/lane; LDS dst wave-uniform (HW adds lane*16)
__device__ __forceinline__ void gload_lds16(const void* g, void* l) {
    __builtin_amdgcn_global_load_lds(
        (const __attribute__((address_space(1))) void*)g,
        (__attribute__((address_space(3))) void*)l, 16, 0, 0);
}

// ======================= kernel 1: fused pre-pass (R6, unchanged) ==========
__global__ __launch_bounds__(256) void k_pre(
        const float* __restrict__ t, const float* __restrict__ X,
        const float* __restrict__ W1, const float* __restrict__ b1,
        const float* __restrict__ W2, const float* __restrict__ b2,
        float* __restrict__ u_out, float* __restrict__ dux,
        float* __restrict__ dut, __hip_bfloat16* __restrict__ S2n,
        __hip_bfloat16* __restrict__ P) {
    __shared__ __align__(16) char smem[51200];
    int tid = threadIdx.x, bid = blockIdx.x;

    if (bid < NFWD) {
        float* s_in  = (float*)smem;                 // [4][101]
        float* c_sh  = (float*)(smem + 1664);        // [4][256]
        float* us_sh = (float*)(smem + 1664 + 4096); // [4][256]
        int i0 = bid * SMF;

        for (int idx = tid; idx < SMF * IN_DIM; idx += 256) {
            int i = idx / IN_DIM, j = idx % IN_DIM;
            s_in[i * IN_DIM + j] = (j == 0) ? t[i0 + i]
                                            : X[(size_t)(i0 + i) * D_IN + (j - 1)];
        }
        __syncthreads();

        int h = tid;
        float z[SMF];
        float bb = b1[h];
#pragma unroll
        for (int i = 0; i < SMF; i++) z[i] = bb;
        const float* wrow = W1 + (size_t)h * IN_DIM;
        for (int j = 0; j < IN_DIM; j++) {
            float w = wrow[j];
#pragma unroll
            for (int i = 0; i < SMF; i++) z[i] += w * s_in[i * IN_DIM + j];
        }
        float w2 = W2[h];
#pragma unroll
        for (int i = 0; i < SMF; i++) {
            float sz, cz;
            sincosf(z[i], &sz, &cz);
            c_sh[i * HID + h]  = w2 * cz;
            us_sh[i * HID + h] = w2 * sz;
            S2n[(size_t)(i0 + i) * HID + h] = __float2bfloat16(-w2 * sz);
        }
        __syncthreads();

        for (int off = 128; off > 0; off >>= 1) {
            if (tid < off) {
#pragma unroll
                for (int i = 0; i < SMF; i++)
                    us_sh[i * HID + tid] += us_sh[i * HID + tid + off];
            }
            __syncthreads();
        }
        if (tid < SMF) u_out[i0 + tid] = us_sh[tid * HID] + b2[0];

        if (tid < IN_DIM) {
            float acc[SMF];
#pragma unroll
            for (int i = 0; i < SMF; i++) acc[i] = 0.f;
            for (int h0 = 0; h0 < HID; h0 += 4) {
                float w0 = W1[(size_t)(h0 + 0) * IN_DIM + tid];
                float w1 = W1[(size_t)(h0 + 1) * IN_DIM + tid];
                float w2_ = W1[(size_t)(h0 + 2) * IN_DIM + tid];
                float w3 = W1[(size_t)(h0 + 3) * IN_DIM + tid];
#pragma unroll
                for (int i = 0; i < SMF; i++)
                    acc[i] += c_sh[i * HID + h0] * w0 + c_sh[i * HID + h0 + 1] * w1
                            + c_sh[i * HID + h0 + 2] * w2_ + c_sh[i * HID + h0 + 3] * w3;
            }
            if (tid == 0) {
                for (int i = 0; i < SMF; i++) dut[i0 + i] = acc[i];
            } else {
                for (int i = 0; i < SMF; i++)
                    dux[(size_t)(i0 + i) * D_IN + (tid - 1)] = acc[i];
            }
        }
    } else if (bid < NFWD + D_IN) {
        int j = bid - NFWD;                       // 0..99
        __hip_bfloat16* Wb = (__hip_bfloat16*)smem;   // [100][256] bf16 = 50 KB
        const float* wrow = W1 + (size_t)tid * IN_DIM + 1;
        for (int k = 0; k < D_IN; k++)
            Wb[k * HID + tid] = __float2bfloat16(wrow[k]);
        __syncthreads();

        int ksub = tid >> 5, h8 = (tid & 31) * 8;
        float aj[8];
#pragma unroll
        for (int e = 0; e < 8; e++) aj[e] = __bfloat162float(Wb[j * HID + h8 + e]);

        for (int kk = 0; kk < 104; kk += 8) {
            int k = kk + ksub;
            if (k < D_IN) {
                short8 v;
#pragma unroll
                for (int e = 0; e < 8; e++) {
                    float b = __bfloat162float(Wb[k * HID + h8 + e]);
                    __hip_bfloat16 hv = __float2bfloat16(aj[e] * b);
                    v[e] = *reinterpret_cast<short*>(&hv);
                }
                *(short8*)&P[(size_t)(j * D_IN + k) * HID + h8] = v;
            }
        }
    } else {
        short8 zero = {0, 0, 0, 0, 0, 0, 0, 0};
        size_t base = (size_t)NSQ * HID;
        for (int idx = tid; idx < (NPAD - NSQ) * HID / 8; idx += 256)
            *(short8*)&P[base + (size_t)idx * 8] = zero;
    }
}

// ======================= kernel 2: H = S2n @ P^T (R6, unchanged) ============
#define BM 128
#define BN 128
#define BK 64
#define NK 4      // 256 / 64
#define NBLK 79   // NPAD / 128

__global__ __launch_bounds__(256) void k_gemm(
        const __hip_bfloat16* __restrict__ A,   // [4096][256] row-major
        const __hip_bfloat16* __restrict__ B,   // [NPAD][256] n-major (=B^T)
        float* __restrict__ C) {                // [4096][10000]
    __shared__ __hip_bfloat16 As[2][BM * BK];   // 2 x 16 KB
    __shared__ __hip_bfloat16 Bs[2][BM * BK];   // 2 x 16 KB

    int bid = blockIdx.x;
    int bm = bid / NBLK, bn = bid % NBLK;
    int m0 = bm * BM, n0 = bn * BN;
    int tid = threadIdx.x;
    int lane = tid & 63, wave = tid >> 6;
    int wm = wave >> 1, wn = wave & 1;   // 2x2 waves, 64x64 out each

    int srow8 = lane >> 3;               // r & 7
    int scol = ((lane & 7) ^ srow8) * 8; // pre-swizzled source col (bf16 elems)

    f32x4 acc[4][4];
#pragma unroll
    for (int i = 0; i < 4; i++)
#pragma unroll
        for (int j = 0; j < 4; j++) acc[i][j] = {0.f, 0.f, 0.f, 0.f};

    auto stage = [&](int buf, int kt) {
        int kc = kt * BK;
#pragma unroll
        for (int i = 0; i < 4; i++) {
            int rb = wave * 32 + i * 8;
            gload_lds16(A + (size_t)(m0 + rb + srow8) * HID + kc + scol,
                        &As[buf][rb * BK]);
            gload_lds16(B + (size_t)(n0 + rb + srow8) * HID + kc + scol,
                        &Bs[buf][rb * BK]);
        }
    };

    stage(0, 0);

    for (int kt = 0; kt < NK; kt++) {
        int cur = kt & 1;
        __syncthreads();                 // buf[cur] staged; readers of buf[cur^1] done
        if (kt + 1 < NK) stage(cur ^ 1, kt + 1);   // prefetch under compute

        const char* Ab = (const char*)As[cur];
        const char* Bb = (const char*)Bs[cur];
        int lo = lane & 15;
        int xr = (lane & 7) << 4;        // row-XOR term (r&7 == lane&7)
#pragma unroll
        for (int kk = 0; kk < 2; kk++) {
            int kbs = (kk * 64 + ((lane >> 4) << 4)) ^ xr;   // swizzled byte-in-row
            short8 af[4], bf4[4];
#pragma unroll
            for (int mi = 0; mi < 4; mi++)
                af[mi] = *(const short8*)(Ab + (wm * 64 + mi * 16 + lo) * 128 + kbs);
#pragma unroll
            for (int ni = 0; ni < 4; ni++)
                bf4[ni] = *(const short8*)(Bb + (wn * 64 + ni * 16 + lo) * 128 + kbs);
            // swapped operands: D = (A.B)^T per-fragment -> lane's f32x4 spans n
#pragma unroll
            for (int mi = 0; mi < 4; mi++)
#pragma unroll
                for (int ni = 0; ni < 4; ni++)
                    acc[mi][ni] = __builtin_amdgcn_mfma_f32_16x16x32_bf16(
                        bf4[ni], af[mi], acc[mi][ni], 0, 0, 0);
        }
    }

    // epilogue: m = lane&15 (fragment col), n = (lane>>4)*4 + reg (consecutive)
    int lo = lane & 15, hi4 = (lane >> 4) << 2;
#pragma unroll
    for (int mi = 0; mi < 4; mi++) {
        int mrow = m0 + wm * 64 + mi * 16 + lo;
#pragma unroll
        for (int ni = 0; ni < 4; ni++) {
            int ncol = n0 + wn * 64 + ni * 16 + hi4;
            if (ncol < NSQ)   // ncol%4==0, NSQ%4==0 -> covers all 4 elements
                *(f32x4*)&C[(size_t)mrow * NSQ + ncol] = acc[mi][ni];
        }
    }
}

extern "C" void kernel_launch(void* const* d_in, const int* in_sizes, int n_in,
                              void* d_out, int out_size, void* d_ws, size_t ws_size,
                              hipStream_t stream) {
    const float* t  = (const float*)d_in[0];
    const float* X  = (const float*)d_in[1];
    const float* W1 = (const float*)d_in[2];
    const float* b1 = (const float*)d_in[3];
    const float* W2 = (const float*)d_in[4];
    const float* b2 = (const float*)d_in[5];

    float* out = (float*)d_out;
    float* u_out = out;                                  // 4096
    float* dux   = out + M_SAMP;                         // 409600
    float* dut   = out + M_SAMP + (size_t)M_SAMP * D_IN; // 4096
    float* H     = dut + M_SAMP;                         // 40,960,000

    char* ws = (char*)d_ws;
    __hip_bfloat16* S2n = (__hip_bfloat16*)ws;                // 2 MB
    __hip_bfloat16* P   = (__hip_bfloat16*)(ws + 2097152);    // 5.18 MB (padded)

    k_pre<<<NFWD + D_IN + 1, 256, 0, stream>>>(t, X, W1, b1, W2, b2,
                                               u_out, dux, dut, S2n, P);
    // ---- ATTRIBUTION EXPERIMENT: k_gemm is idempotent (full overwrite of H
    // from unchanged S2n/P). Launch 3x: total_R7 - total_R6 = 2 * T_gemm.
    k_gemm<<<(M_SAMP / BM) * NBLK, 256, 0, stream>>>(S2n, P, H);
    k_gemm<<<(M_SAMP / BM) * NBLK, 256, 0, stream>>>(S2n, P, H);
    k_gemm<<<(M_SAMP / BM) * NBLK, 256, 0, stream>>>(S2n, P, H);
}

// Round 8
// 110.450 us; speedup vs baseline: 1.9685x; 1.9685x over previous
//
#include <hip/hip_runtime.h>
#include <hip/hip_bf16.h>

#define M_SAMP 4096
#define D_IN   100
#define HID    256
#define IN_DIM 101
#define NSQ    10000   // 100*100
#define NPAD   10240   // 40*256, padded rows of P
#define SMF    4       // samples per fwd block
#define NFWD   (M_SAMP / SMF)   // 1024 fwd blocks

typedef __attribute__((ext_vector_type(8))) short short8;
typedef __attribute__((ext_vector_type(4))) float f32x4;

// async global->LDS, 16B/lane; LDS dst wave-uniform (HW adds lane*16)
__device__ __forceinline__ void gload_lds16(const void* g, void* l) {
    __builtin_amdgcn_global_load_lds(
        (const __attribute__((address_space(1))) void*)g,
        (__attribute__((address_space(3))) void*)l, 16, 0, 0);
}

// ======================= kernel 1: fused pre-pass (R6; pad const only) ======
__global__ __launch_bounds__(256) void k_pre(
        const float* __restrict__ t, const float* __restrict__ X,
        const float* __restrict__ W1, const float* __restrict__ b1,
        const float* __restrict__ W2, const float* __restrict__ b2,
        float* __restrict__ u_out, float* __restrict__ dux,
        float* __restrict__ dut, __hip_bfloat16* __restrict__ S2n,
        __hip_bfloat16* __restrict__ P) {
    __shared__ __align__(16) char smem[51200];
    int tid = threadIdx.x, bid = blockIdx.x;

    if (bid < NFWD) {
        float* s_in  = (float*)smem;                 // [4][101]
        float* c_sh  = (float*)(smem + 1664);        // [4][256]
        float* us_sh = (float*)(smem + 1664 + 4096); // [4][256]
        int i0 = bid * SMF;

        for (int idx = tid; idx < SMF * IN_DIM; idx += 256) {
            int i = idx / IN_DIM, j = idx % IN_DIM;
            s_in[i * IN_DIM + j] = (j == 0) ? t[i0 + i]
                                            : X[(size_t)(i0 + i) * D_IN + (j - 1)];
        }
        __syncthreads();

        int h = tid;
        float z[SMF];
        float bb = b1[h];
#pragma unroll
        for (int i = 0; i < SMF; i++) z[i] = bb;
        const float* wrow = W1 + (size_t)h * IN_DIM;
        for (int j = 0; j < IN_DIM; j++) {
            float w = wrow[j];
#pragma unroll
            for (int i = 0; i < SMF; i++) z[i] += w * s_in[i * IN_DIM + j];
        }
        float w2 = W2[h];
#pragma unroll
        for (int i = 0; i < SMF; i++) {
            float sz, cz;
            sincosf(z[i], &sz, &cz);
            c_sh[i * HID + h]  = w2 * cz;
            us_sh[i * HID + h] = w2 * sz;
            S2n[(size_t)(i0 + i) * HID + h] = __float2bfloat16(-w2 * sz);
        }
        __syncthreads();

        for (int off = 128; off > 0; off >>= 1) {
            if (tid < off) {
#pragma unroll
                for (int i = 0; i < SMF; i++)
                    us_sh[i * HID + tid] += us_sh[i * HID + tid + off];
            }
            __syncthreads();
        }
        if (tid < SMF) u_out[i0 + tid] = us_sh[tid * HID] + b2[0];

        if (tid < IN_DIM) {
            float acc[SMF];
#pragma unroll
            for (int i = 0; i < SMF; i++) acc[i] = 0.f;
            for (int h0 = 0; h0 < HID; h0 += 4) {
                float w0 = W1[(size_t)(h0 + 0) * IN_DIM + tid];
                float w1 = W1[(size_t)(h0 + 1) * IN_DIM + tid];
                float w2_ = W1[(size_t)(h0 + 2) * IN_DIM + tid];
                float w3 = W1[(size_t)(h0 + 3) * IN_DIM + tid];
#pragma unroll
                for (int i = 0; i < SMF; i++)
                    acc[i] += c_sh[i * HID + h0] * w0 + c_sh[i * HID + h0 + 1] * w1
                            + c_sh[i * HID + h0 + 2] * w2_ + c_sh[i * HID + h0 + 3] * w3;
            }
            if (tid == 0) {
                for (int i = 0; i < SMF; i++) dut[i0 + i] = acc[i];
            } else {
                for (int i = 0; i < SMF; i++)
                    dux[(size_t)(i0 + i) * D_IN + (tid - 1)] = acc[i];
            }
        }
    } else if (bid < NFWD + D_IN) {
        int j = bid - NFWD;                       // 0..99
        __hip_bfloat16* Wb = (__hip_bfloat16*)smem;   // [100][256] bf16 = 50 KB
        const float* wrow = W1 + (size_t)tid * IN_DIM + 1;
        for (int k = 0; k < D_IN; k++)
            Wb[k * HID + tid] = __float2bfloat16(wrow[k]);
        __syncthreads();

        int ksub = tid >> 5, h8 = (tid & 31) * 8;
        float aj[8];
#pragma unroll
        for (int e = 0; e < 8; e++) aj[e] = __bfloat162float(Wb[j * HID + h8 + e]);

        for (int kk = 0; kk < 104; kk += 8) {
            int k = kk + ksub;
            if (k < D_IN) {
                short8 v;
#pragma unroll
                for (int e = 0; e < 8; e++) {
                    float b = __bfloat162float(Wb[k * HID + h8 + e]);
                    __hip_bfloat16 hv = __float2bfloat16(aj[e] * b);
                    v[e] = *reinterpret_cast<short*>(&hv);
                }
                *(short8*)&P[(size_t)(j * D_IN + k) * HID + h8] = v;
            }
        }
    } else {
        // zero pad rows [10000, 10240)
        short8 zero = {0, 0, 0, 0, 0, 0, 0, 0};
        size_t base = (size_t)NSQ * HID;
        for (int idx = tid; idx < (NPAD - NSQ) * HID / 8; idx += 256)
            *(short8*)&P[base + (size_t)idx * 8] = zero;
    }
}

// ============ kernel 2: H = S2n @ P^T — v2: 64x256 tile, LDS epilogue =======
// BK=32 (64 B/row tiles), 40 KB LDS -> 4 blocks/CU. Both-sides swizzle with
// involution chunk ^= (row>>1)&3 (even 32 B/bank on all LDS ops). Epilogue
// transposes acc through LDS so each wave-store is 1024 contiguous bytes.
#define BM 64
#define BN 256
#define BK 32
#define NK 8      // 256/32
#define NBT 40    // NPAD/256

__global__ __launch_bounds__(256) void k_gemm(
        const __hip_bfloat16* __restrict__ A,   // [4096][256] row-major (S2n)
        const __hip_bfloat16* __restrict__ B,   // [NPAD][256] n-major (P)
        float* __restrict__ C) {                // [4096][10000]
    // layout: As buf0 @0 (4KB), As buf1 @4096, Bs buf0 @8192 (16KB), Bs buf1 @24576
    __shared__ __align__(16) char smem[40960];

    int b0 = blockIdx.x;
    int s = (b0 & 7) * 320 + (b0 >> 3);        // XCD-bijective (2560 = 8*320)
    int m0 = (s / NBT) * BM, n0 = (s % NBT) * BN;
    int tid = threadIdx.x;
    int lane = tid & 63, wave = tid >> 6;
    int wm = wave >> 1, wn = wave & 1;         // 2x2 waves: 32m x 128n each

    // staging geometry: lane l -> local row l>>2, lds chunk l&3;
    // source chunk pre-swizzled: c_src = (l&3) ^ ((l>>3)&3)  [= (r>>1)&3]
    int rl = lane >> 2;
    int csrc = (((lane & 3) ^ ((lane >> 3) & 3))) * 8;   // bf16 elems

    f32x4 acc[2][8];
#pragma unroll
    for (int i = 0; i < 2; i++)
#pragma unroll
        for (int j = 0; j < 8; j++) acc[i][j] = {0.f, 0.f, 0.f, 0.f};

    auto stage = [&](int buf, int kt) {
        int kc = kt * BK;
        // A: 64 rows x 64 B -> 1 gload/thread; wave w covers rows w*16..+15
        gload_lds16(A + (size_t)(m0 + wave * 16 + rl) * HID + kc + csrc,
                    smem + buf * 4096 + wave * 1024);
        // B: 256 rows -> 4 gloads/thread; wave w covers rows w*64..+63
#pragma unroll
        for (int i = 0; i < 4; i++)
            gload_lds16(B + (size_t)(n0 + wave * 64 + i * 16 + rl) * HID + kc + csrc,
                        smem + 8192 + buf * 16384 + wave * 4096 + i * 1024);
    };

    stage(0, 0);

    int lo = lane & 15, g = lane >> 4;
    for (int kt = 0; kt < NK; kt++) {
        int cur = kt & 1;
        __syncthreads();                        // buf[cur] ready; prev readers done
        if (kt + 1 < NK) stage(cur ^ 1, kt + 1);

        const char* Ab = (const char*)smem + cur * 4096;
        const char* Bb = (const char*)smem + 8192 + cur * 16384;
        short8 af[2], bf[8];
#pragma unroll
        for (int mi = 0; mi < 2; mi++) {
            int r = wm * 32 + mi * 16 + lo;
            af[mi] = *(const short8*)(Ab + r * 64 + ((g ^ ((r >> 1) & 3)) << 4));
        }
#pragma unroll
        for (int ni = 0; ni < 8; ni++) {
            int r = wn * 128 + ni * 16 + lo;
            bf[ni] = *(const short8*)(Bb + r * 64 + ((g ^ ((r >> 1) & 3)) << 4));
        }
        // swapped operands: lane&15 -> m, (lane>>4)*4+reg -> n (R5-verified)
#pragma unroll
        for (int mi = 0; mi < 2; mi++)
#pragma unroll
            for (int ni = 0; ni < 8; ni++)
                acc[mi][ni] = __builtin_amdgcn_mfma_f32_16x16x32_bf16(
                    bf[ni], af[mi], acc[mi][ni], 0, 0, 0);
    }

    // ---------- epilogue: acc -> LDS [32][260] f32 -> contiguous 1-KB stores ----
    float* lds2 = (float*)smem;
#pragma unroll
    for (int c = 0; c < 2; c++) {
        __syncthreads();    // staging reads (c=0) / prior chunk stores (c=1) done
        if (wm == c) {
#pragma unroll
            for (int mi = 0; mi < 2; mi++) {
                int mloc = mi * 16 + lo;
#pragma unroll
                for (int ni = 0; ni < 8; ni++) {
                    int nb = wn * 128 + ni * 16 + g * 4;
                    *(f32x4*)&lds2[mloc * 260 + nb] = acc[mi][ni];
                }
            }
        }
        __syncthreads();
#pragma unroll
        for (int si = 0; si < 8; si++) {
            int idx = tid + 256 * si;           // 0..2047
            int row = idx >> 6, c4 = (idx & 63) * 4;
            int n = n0 + c4;
            if (n < NSQ)
                *(f32x4*)&C[(size_t)(m0 + c * 32 + row) * NSQ + n] =
                    *(f32x4*)&lds2[row * 260 + c4];
        }
    }
}

extern "C" void kernel_launch(void* const* d_in, const int* in_sizes, int n_in,
                              void* d_out, int out_size, void* d_ws, size_t ws_size,
                              hipStream_t stream) {
    const float* t  = (const float*)d_in[0];
    const float* X  = (const float*)d_in[1];
    const float* W1 = (const float*)d_in[2];
    const float* b1 = (const float*)d_in[3];
    const float* W2 = (const float*)d_in[4];
    const float* b2 = (const float*)d_in[5];

    float* out = (float*)d_out;
    float* u_out = out;                                  // 4096
    float* dux   = out + M_SAMP;                         // 409600
    float* dut   = out + M_SAMP + (size_t)M_SAMP * D_IN; // 4096
    float* H     = dut + M_SAMP;                         // 40,960,000

    char* ws = (char*)d_ws;
    __hip_bfloat16* S2n = (__hip_bfloat16*)ws;                // 2 MB
    __hip_bfloat16* P   = (__hip_bfloat16*)(ws + 2097152);    // 5.24 MB (padded)

    k_pre<<<NFWD + D_IN + 1, 256, 0, stream>>>(t, X, W1, b1, W2, b2,
                                               u_out, dux, dut, S2n, P);
    k_gemm<<<(M_SAMP / BM) * NBT, 256, 0, stream>>>(S2n, P, H);
}